// Round 15
// baseline (262.061 us; speedup 1.0000x reference)
//
#include <hip/hip_runtime.h>
#include <hip/hip_bf16.h>

#define LSEQ 2048
#define BB 2
#define DD 128
#define HH 8
#define HD 32

#define QSCALE 0.25503486f           // (1/sqrt(32)) * log2(e)  -> use exp2

typedef __bf16 bf8_t __attribute__((ext_vector_type(8)));
typedef __bf16 bf4_t __attribute__((ext_vector_type(4)));
typedef float f4_t __attribute__((ext_vector_type(4)));

// raw 2^x (scores are small & well-conditioned; no denormal/edge fixup needed)
static __device__ __forceinline__ float fexp2(float x) {
#if __has_builtin(__builtin_amdgcn_exp2f)
    return __builtin_amdgcn_exp2f(x);
#else
    float r;
    asm("v_exp_f32 %0, %1" : "=v"(r) : "v"(x));
    return r;
#endif
}

// ---------------- kernel A: QK-GEMM + wv sigmoid + zero out ----------
// blocks 0..511   : Q/K = (x+pe) @ W (+bias); 64 rows x 64 cols per block
// blocks 512..639 : w[hb][k] = sigmoid(x[b,L-1-k] . Wv[:,h])
// blocks 640..671 : zero out (float4) — k_F accumulates into out directly
__global__ __launch_bounds__(256) void k_A(const float* __restrict__ x,
                                           const float* __restrict__ pe,
                                           const float* __restrict__ Wq,
                                           const float* __restrict__ Wk,
                                           const float* __restrict__ Wv,
                                           const float* __restrict__ bq,
                                           const float* __restrict__ bk,
                                           float* __restrict__ w,
                                           __bf16* __restrict__ Qb,
                                           __bf16* __restrict__ Kb,
                                           float* __restrict__ out) {
    __shared__ __align__(16) char smem[34816];
    int gb = blockIdx.x;
    int tid = threadIdx.x;

    if (gb < 512) {
        // ---- QK GEMM role: 64 rows x 64 cols ----
        __bf16* xs = (__bf16*)smem;                   // 64 x 136
        __bf16* Wt = (__bf16*)(smem + 64 * 136 * 2);  // 64 x 136 (c-major, transposed)
        int jr = gb >> 3, y = gb & 7;
        int row0 = jr * 64;
        bool isK = y >= 4;
        int cbase = (y & 3) * 64;
        const float* W = isK ? Wk : Wq;

        // stage x+pe -> bf16 LDS (64 rows x 128 cols), float4 loads
        #pragma unroll
        for (int i = 0; i < 8; i++) {
            int idx4 = tid + i * 256;                 // 0..2047 float4s
            int row = idx4 >> 5, col4 = idx4 & 31;
            float4 xv = ((const float4*)x)[row0 * 32 + idx4];
            float4 pv = ((const float4*)pe)[((row0 + row) & (LSEQ - 1)) * 32 + col4];
            bf4_t o = {(__bf16)(xv.x + pv.x), (__bf16)(xv.y + pv.y),
                       (__bf16)(xv.z + pv.z), (__bf16)(xv.w + pv.w)};
            *(bf4_t*)&xs[row * 136 + col4 * 4] = o;
        }
        // stage W stripe transposed via in-register 4x4 transpose:
        // 4 coalesced float4 loads (rows d0..d0+3) -> 4 ds_write_b64 along d.
        // (r14 lesson: 32 scalar ds_write_u16/thread was the k_A staging cost)
        #pragma unroll
        for (int i2 = 0; i2 < 2; i2++) {
            int idx = tid + i2 * 256;                 // 0..511
            int dblk = idx >> 4;                      // 0..31
            int c4 = (idx & 15) * 4;                  // 0..60
            int d0 = dblk * 4;
            float4 L0 = *(const float4*)(W + (d0 + 0) * 256 + cbase + c4);
            float4 L1 = *(const float4*)(W + (d0 + 1) * 256 + cbase + c4);
            float4 L2 = *(const float4*)(W + (d0 + 2) * 256 + cbase + c4);
            float4 L3 = *(const float4*)(W + (d0 + 3) * 256 + cbase + c4);
            *(bf4_t*)&Wt[(c4 + 0) * 136 + d0] =
                (bf4_t){(__bf16)L0.x, (__bf16)L1.x, (__bf16)L2.x, (__bf16)L3.x};
            *(bf4_t*)&Wt[(c4 + 1) * 136 + d0] =
                (bf4_t){(__bf16)L0.y, (__bf16)L1.y, (__bf16)L2.y, (__bf16)L3.y};
            *(bf4_t*)&Wt[(c4 + 2) * 136 + d0] =
                (bf4_t){(__bf16)L0.z, (__bf16)L1.z, (__bf16)L2.z, (__bf16)L3.z};
            *(bf4_t*)&Wt[(c4 + 3) * 136 + d0] =
                (bf4_t){(__bf16)L0.w, (__bf16)L1.w, (__bf16)L2.w, (__bf16)L3.w};
        }
        __syncthreads();

        int wid = tid >> 6, lane = tid & 63;
        int lm = lane & 15, lq = lane >> 4;
        int c0loc = wid * 16;
        f4_t acc0 = {0,0,0,0}, acc1 = {0,0,0,0}, acc2 = {0,0,0,0}, acc3 = {0,0,0,0};
        #pragma unroll
        for (int s = 0; s < 4; s++) {
            bf8_t bw = *(const bf8_t*)&Wt[(c0loc + lm) * 136 + lq * 8 + s * 32];
            bf8_t a0 = *(const bf8_t*)&xs[(0  + lm) * 136 + lq * 8 + s * 32];
            bf8_t a1 = *(const bf8_t*)&xs[(16 + lm) * 136 + lq * 8 + s * 32];
            bf8_t a2 = *(const bf8_t*)&xs[(32 + lm) * 136 + lq * 8 + s * 32];
            bf8_t a3 = *(const bf8_t*)&xs[(48 + lm) * 136 + lq * 8 + s * 32];
            acc0 = __builtin_amdgcn_mfma_f32_16x16x32_bf16(a0, bw, acc0, 0, 0, 0);
            acc1 = __builtin_amdgcn_mfma_f32_16x16x32_bf16(a1, bw, acc1, 0, 0, 0);
            acc2 = __builtin_amdgcn_mfma_f32_16x16x32_bf16(a2, bw, acc2, 0, 0, 0);
            acc3 = __builtin_amdgcn_mfma_f32_16x16x32_bf16(a3, bw, acc3, 0, 0, 0);
        }
        int c = cbase + c0loc + lm;                   // 0..255
        float bv = (isK ? bk : bq)[c];
        float qs = isK ? 1.f : QSCALE;
        __bf16* Out = isK ? Kb : Qb;
        int h = c >> 5, hd = c & 31;
        f4_t accs[4] = {acc0, acc1, acc2, acc3};
        #pragma unroll
        for (int rs = 0; rs < 4; rs++) {
            #pragma unroll
            for (int r = 0; r < 4; r++) {
                int row = row0 + rs * 16 + lq * 4 + r;   // = b*2048 + l
                int b_ = row >> 11, l = row & (LSEQ - 1);
                Out[((h * BB + b_) * LSEQ + l) * HD + hd] =
                    (__bf16)((accs[rs][r] + bv) * qs);
            }
        }
    } else if (gb < 640) {
        // ---- wv sigmoid role ----
        float* xsf = (float*)smem;                    // 32*132
        float* wvf = (float*)(smem + 32 * 132 * 4);   // 1024
        int r0 = (gb - 512) * 32;
        for (int i = 0; i < 16; i++) {
            int idx = tid + i * 256;
            xsf[(idx >> 7) * 132 + (idx & 127)] = x[r0 * 128 + idx];
        }
        for (int i = 0; i < 4; i++) {
            int idx = tid + i * 256;
            wvf[idx] = Wv[idx];
        }
        __syncthreads();
        int rl = tid >> 3, h = tid & 7;
        float acc = 0.f;
        #pragma unroll 8
        for (int d = 0; d < 128; d++) acc += xsf[rl * 132 + d] * wvf[d * 8 + h];
        float sg = 1.f / (1.f + __expf(-acc));
        int r = r0 + rl;
        int b = r >> 11, l = r & (LSEQ - 1);
        w[(h * BB + b) * LSEQ + (LSEQ - 1 - l)] = sg;
    } else {
        float4 z = {0.f, 0.f, 0.f, 0.f};
        ((float4*)out)[(gb - 640) * 256 + tid] = z;   // 32 blocks x 4KB = 128KB
    }
}

// ---------------- kernel F: LDS-staged K, den + scatter + fused pooling -----
// grid (32 q-stripes, 16 hb) = 512 blocks, 512 threads = 8 waves, 64 q/block.
// Load-balance swizzle: xm = hb>=8 ? 31-x : x pairs heavy/light triangles on
// each CU (linear blocks b and b+256 co-reside).
// Sloc is FLOAT with native ds_add_f32 atomics: drops the fixed-point
// __float2int_rn per scatter element (67M cvts) and the FPSCALE round trip.
// NOTE (r13 lesson): no manual reg-staging of K — compiler pipelines better.
// phase 1: den over all k, chunk-major (4 x 32KB LDS chunks); pair combine.
// phase 2: triangle scatter into 2048-bin float Sloc, chunks descending
//          (chunk 3 resident from phase 1), j-parity split within wave pair.
// phase 3: pooling is linear in S -> 3-tap stencil on this block's partials,
//          float atomics into out (reciprocal-multiply).
__global__ __launch_bounds__(512) void k_F(const __bf16* __restrict__ Qb,
                                           const __bf16* __restrict__ Kb,
                                           const float* __restrict__ w,
                                           float* __restrict__ out) {
    __shared__ __align__(16) __bf16 Kl[512 * HD];    // 32 KB
    __shared__ __align__(16) float  wl[2048];        // 8 KB
    __shared__ __align__(16) float  Sloc[2048];      // 8 KB
    __shared__ float dred[128];

    int hb = blockIdx.y;
    int xm = (hb >= 8) ? (31 - blockIdx.x) : blockIdx.x;   // load-balance swizzle
    int q0 = xm << 6;                            // 64 q rows per block
    int tid = threadIdx.x;
    int wid = tid >> 6, lane = tid & 63;
    int lm = lane & 15, lq = lane >> 4;
    int g = wid >> 1, h = wid & 1;               // 4 q-groups x 2 k-halves
    int qg0 = q0 + g * 16;

    float4 zf4 = {0.f, 0.f, 0.f, 0.f};
    ((float4*)Sloc)[tid] = zf4;                  // 512*16B = 8KB

    const __bf16* Qhb = Qb + hb * LSEQ * HD;
    const __bf16* Khb = Kb + hb * LSEQ * HD;

    // stage w[hb] (8KB, coalesced int4)
    ((float4*)wl)[tid] = ((const float4*)(w + hb * LSEQ))[tid];

    bf8_t aq = *(const bf8_t*)(Qhb + (qg0 + lm) * HD + lq * 8);

    // ---- phase 1: denominators over all k, chunk-staged ----
    float dsum[4] = {0.f, 0.f, 0.f, 0.f};
    for (int c = 0; c < 4; c++) {
        __syncthreads();                         // prior chunk compute done
        const int4* gsrc = (const int4*)(Khb + c * 512 * HD);
        #pragma unroll
        for (int i = 0; i < 4; i++) {
            int idx = tid + i * 512;
            ((int4*)Kl)[idx] = gsrc[idx];        // 32KB coalesced
        }
        __syncthreads();
        #pragma unroll 4
        for (int sl = h; sl < 32; sl += 2) {     // 16 subtiles per wave
            bf8_t bk_ = *(const bf8_t*)&Kl[(sl * 16 + lm) * HD + lq * 8];
            f4_t z = {0.f, 0.f, 0.f, 0.f};
            f4_t sc = __builtin_amdgcn_mfma_f32_16x16x32_bf16(aq, bk_, z, 0, 0, 0);
            #pragma unroll
            for (int r = 0; r < 4; r++) dsum[r] += fexp2(sc[r]);
        }
    }
    #pragma unroll
    for (int r = 0; r < 4; r++) {
        float v = dsum[r];
        v += __shfl_xor(v, 1);
        v += __shfl_xor(v, 2);
        v += __shfl_xor(v, 4);
        v += __shfl_xor(v, 8);
        dsum[r] = v;
    }
    if (lm == 0) {
        #pragma unroll
        for (int r = 0; r < 4; r++) dred[wid * 16 + lq * 4 + r] = dsum[r];
    }
    __syncthreads();
    float rdv[4];
    #pragma unroll
    for (int r = 0; r < 4; r++) {
        int base = g * 32 + lq * 4 + r;          // pair (g,h=0)+(g,h=1)
        rdv[r] = 1.0f / (dred[base] + dred[base + 16]);
    }

    // ---- phase 2: triangle scatter, chunks descending (3 is resident) ----
    int jb = qg0 >> 4;                           // boundary subtile index
    int c0 = q0 >> 9;                            // first chunk with k >= q0
    int qrow = qg0 + lq * 4;
    for (int c = 3; c >= c0; c--) {
        if (c != 3) {
            __syncthreads();
            const int4* gsrc = (const int4*)(Khb + c * 512 * HD);
            #pragma unroll
            for (int i = 0; i < 4; i++) {
                int idx = tid + i * 512;
                ((int4*)Kl)[idx] = gsrc[idx];
            }
            __syncthreads();
        }
        int jlo = jb > c * 32 ? jb : c * 32;
        int jhi = (c + 1) * 32;
        int js = jlo + ((jlo ^ h) & 1);          // first j with j&1 == h
        for (int j = js; j < jhi; j += 2) {
            int krow = j * 16 - c * 512 + lm;    // row within chunk
            bf8_t bk_ = *(const bf8_t*)&Kl[krow * HD + lq * 8];
            f4_t z = {0.f, 0.f, 0.f, 0.f};
            f4_t sc = __builtin_amdgcn_mfma_f32_16x16x32_bf16(aq, bk_, z, 0, 0, 0);
            float wv = wl[j * 16 + lm];
            int base = j * 16 + lm - qrow;       // m for r=0
            if (j == jb) {                       // boundary: mask m>=0
                #pragma unroll
                for (int r = 0; r < 4; r++) {
                    int m = base - r;
                    if (m >= 0)
                        atomicAdd(&Sloc[m], fexp2(sc[r]) * rdv[r] * wv);
                }
            } else {                             // strictly above diagonal
                #pragma unroll
                for (int r = 0; r < 4; r++)
                    atomicAdd(&Sloc[base - r], fexp2(sc[r]) * rdv[r] * wv);
            }
        }
    }
    __syncthreads();

    // ---- phase 3: fused pooling — stencil on partials, float atomics ----
    // out[(b*2048+m)*8+h] += (Sloc[m-1]+Sloc[m]+Sloc[m+1]) * scale(edge)
    const float SC3 = 1.0f / 3.0f;
    const float SC2 = 0.5f;
    int hh = hb >> 1, b = hb & 1;
    float* obase = out + (b * LSEQ) * 8 + hh;
    int M = LSEQ - q0;                           // bins [0,M) are (possibly) set
    int top = (M + 1 < LSEQ) ? M + 1 : LSEQ;     // stencil reach
    for (int m = tid; m < top; m += 512) {
        float s = Sloc[m];
        float sc = SC3;
        if (m > 0) s += Sloc[m - 1]; else sc = SC2;
        if (m < LSEQ - 1) s += Sloc[m + 1]; else sc = SC2;
        if (s != 0.f)
            atomicAdd(&obase[m * 8], s * sc);
    }
}

extern "C" void kernel_launch(void* const* d_in, const int* in_sizes, int n_in,
                              void* d_out, int out_size, void* d_ws, size_t ws_size,
                              hipStream_t stream) {
    const float* x  = (const float*)d_in[0];
    const float* pe = (const float*)d_in[1];
    const float* Wq = (const float*)d_in[2];
    const float* bq = (const float*)d_in[3];
    const float* Wk = (const float*)d_in[4];
    const float* bk = (const float*)d_in[5];
    const float* Wv = (const float*)d_in[6];
    float* out = (float*)d_out;

    char* ws = (char*)d_ws;
    float*  w   = (float*)(ws);                            // 128 KB
    __bf16* Qb  = (__bf16*)(ws + 131072);                  // 2 MB
    __bf16* Kb  = (__bf16*)(ws + 131072 + 2097152);        // 2 MB

    k_A<<<672, 256, 0, stream>>>(x, pe, Wq, Wk, Wv, bq, bk, w, Qb, Kb, out);
    k_F<<<dim3(32, 16), 512, 0, stream>>>(Qb, Kb, w, out);
}

// Round 16
// 108.052 us; speedup vs baseline: 2.4253x; 2.4253x over previous
//
#include <hip/hip_runtime.h>
#include <hip/hip_bf16.h>

#define LSEQ 2048
#define BB 2
#define DD 128
#define HH 8
#define HD 32

#define FPSCALE 524288.0f            // 2^19 fixed-point scale for S
#define RFPSCALE (1.0f / 524288.0f)
#define QSCALE 0.25503486f           // (1/sqrt(32)) * log2(e)  -> use exp2

typedef __bf16 bf8_t __attribute__((ext_vector_type(8)));
typedef __bf16 bf4_t __attribute__((ext_vector_type(4)));
typedef float f4_t __attribute__((ext_vector_type(4)));

// raw 2^x (scores are small & well-conditioned; no denormal/edge fixup needed)
static __device__ __forceinline__ float fexp2(float x) {
#if __has_builtin(__builtin_amdgcn_exp2f)
    return __builtin_amdgcn_exp2f(x);
#else
    float r;
    asm("v_exp_f32 %0, %1" : "=v"(r) : "v"(x));
    return r;
#endif
}

// ---------------- kernel A: QK-GEMM + wv sigmoid + zero out ----------
// blocks 0..511   : Q/K = (x+pe) @ W (+bias); 64 rows x 64 cols per block
// blocks 512..639 : w[hb][k] = sigmoid(x[b,L-1-k] . Wv[:,h]) * FPSCALE
// blocks 640..671 : zero out (float4) — k_F accumulates into out directly
__global__ __launch_bounds__(256) void k_A(const float* __restrict__ x,
                                           const float* __restrict__ pe,
                                           const float* __restrict__ Wq,
                                           const float* __restrict__ Wk,
                                           const float* __restrict__ Wv,
                                           const float* __restrict__ bq,
                                           const float* __restrict__ bk,
                                           float* __restrict__ w,
                                           __bf16* __restrict__ Qb,
                                           __bf16* __restrict__ Kb,
                                           float* __restrict__ out) {
    __shared__ __align__(16) char smem[34816];
    int gb = blockIdx.x;
    int tid = threadIdx.x;

    if (gb < 512) {
        // ---- QK GEMM role: 64 rows x 64 cols ----
        __bf16* xs = (__bf16*)smem;                   // 64 x 136
        __bf16* Wt = (__bf16*)(smem + 64 * 136 * 2);  // 64 x 136 (c-major, transposed)
        int jr = gb >> 3, y = gb & 7;
        int row0 = jr * 64;
        bool isK = y >= 4;
        int cbase = (y & 3) * 64;
        const float* W = isK ? Wk : Wq;

        // stage x+pe -> bf16 LDS (64 rows x 128 cols), float4 loads
        #pragma unroll
        for (int i = 0; i < 8; i++) {
            int idx4 = tid + i * 256;                 // 0..2047 float4s
            int row = idx4 >> 5, col4 = idx4 & 31;
            float4 xv = ((const float4*)x)[row0 * 32 + idx4];
            float4 pv = ((const float4*)pe)[((row0 + row) & (LSEQ - 1)) * 32 + col4];
            bf4_t o = {(__bf16)(xv.x + pv.x), (__bf16)(xv.y + pv.y),
                       (__bf16)(xv.z + pv.z), (__bf16)(xv.w + pv.w)};
            *(bf4_t*)&xs[row * 136 + col4 * 4] = o;
        }
        // stage W stripe transposed via in-register 4x4 transpose:
        // 4 coalesced float4 loads (rows d0..d0+3) -> 4 ds_write_b64 along d.
        // (r14/r15: replaces 32 scalar ds_write_u16/thread; measured ~neutral+)
        #pragma unroll
        for (int i2 = 0; i2 < 2; i2++) {
            int idx = tid + i2 * 256;                 // 0..511
            int dblk = idx >> 4;                      // 0..31
            int c4 = (idx & 15) * 4;                  // 0..60
            int d0 = dblk * 4;
            float4 L0 = *(const float4*)(W + (d0 + 0) * 256 + cbase + c4);
            float4 L1 = *(const float4*)(W + (d0 + 1) * 256 + cbase + c4);
            float4 L2 = *(const float4*)(W + (d0 + 2) * 256 + cbase + c4);
            float4 L3 = *(const float4*)(W + (d0 + 3) * 256 + cbase + c4);
            *(bf4_t*)&Wt[(c4 + 0) * 136 + d0] =
                (bf4_t){(__bf16)L0.x, (__bf16)L1.x, (__bf16)L2.x, (__bf16)L3.x};
            *(bf4_t*)&Wt[(c4 + 1) * 136 + d0] =
                (bf4_t){(__bf16)L0.y, (__bf16)L1.y, (__bf16)L2.y, (__bf16)L3.y};
            *(bf4_t*)&Wt[(c4 + 2) * 136 + d0] =
                (bf4_t){(__bf16)L0.z, (__bf16)L1.z, (__bf16)L2.z, (__bf16)L3.z};
            *(bf4_t*)&Wt[(c4 + 3) * 136 + d0] =
                (bf4_t){(__bf16)L0.w, (__bf16)L1.w, (__bf16)L2.w, (__bf16)L3.w};
        }
        __syncthreads();

        int wid = tid >> 6, lane = tid & 63;
        int lm = lane & 15, lq = lane >> 4;
        int c0loc = wid * 16;
        f4_t acc0 = {0,0,0,0}, acc1 = {0,0,0,0}, acc2 = {0,0,0,0}, acc3 = {0,0,0,0};
        #pragma unroll
        for (int s = 0; s < 4; s++) {
            bf8_t bw = *(const bf8_t*)&Wt[(c0loc + lm) * 136 + lq * 8 + s * 32];
            bf8_t a0 = *(const bf8_t*)&xs[(0  + lm) * 136 + lq * 8 + s * 32];
            bf8_t a1 = *(const bf8_t*)&xs[(16 + lm) * 136 + lq * 8 + s * 32];
            bf8_t a2 = *(const bf8_t*)&xs[(32 + lm) * 136 + lq * 8 + s * 32];
            bf8_t a3 = *(const bf8_t*)&xs[(48 + lm) * 136 + lq * 8 + s * 32];
            acc0 = __builtin_amdgcn_mfma_f32_16x16x32_bf16(a0, bw, acc0, 0, 0, 0);
            acc1 = __builtin_amdgcn_mfma_f32_16x16x32_bf16(a1, bw, acc1, 0, 0, 0);
            acc2 = __builtin_amdgcn_mfma_f32_16x16x32_bf16(a2, bw, acc2, 0, 0, 0);
            acc3 = __builtin_amdgcn_mfma_f32_16x16x32_bf16(a3, bw, acc3, 0, 0, 0);
        }
        int c = cbase + c0loc + lm;                   // 0..255
        float bv = (isK ? bk : bq)[c];
        float qs = isK ? 1.f : QSCALE;
        __bf16* Out = isK ? Kb : Qb;
        int h = c >> 5, hd = c & 31;
        f4_t accs[4] = {acc0, acc1, acc2, acc3};
        #pragma unroll
        for (int rs = 0; rs < 4; rs++) {
            #pragma unroll
            for (int r = 0; r < 4; r++) {
                int row = row0 + rs * 16 + lq * 4 + r;   // = b*2048 + l
                int b_ = row >> 11, l = row & (LSEQ - 1);
                Out[((h * BB + b_) * LSEQ + l) * HD + hd] =
                    (__bf16)((accs[rs][r] + bv) * qs);
            }
        }
    } else if (gb < 640) {
        // ---- wv sigmoid role (FPSCALE folded in) ----
        float* xsf = (float*)smem;                    // 32*132
        float* wvf = (float*)(smem + 32 * 132 * 4);   // 1024
        int r0 = (gb - 512) * 32;
        for (int i = 0; i < 16; i++) {
            int idx = tid + i * 256;
            xsf[(idx >> 7) * 132 + (idx & 127)] = x[r0 * 128 + idx];
        }
        for (int i = 0; i < 4; i++) {
            int idx = tid + i * 256;
            wvf[idx] = Wv[idx];
        }
        __syncthreads();
        int rl = tid >> 3, h = tid & 7;
        float acc = 0.f;
        #pragma unroll 8
        for (int d = 0; d < 128; d++) acc += xsf[rl * 132 + d] * wvf[d * 8 + h];
        float sg = 1.f / (1.f + __expf(-acc));
        int r = r0 + rl;
        int b = r >> 11, l = r & (LSEQ - 1);
        w[(h * BB + b) * LSEQ + (LSEQ - 1 - l)] = sg * FPSCALE;
    } else {
        float4 z = {0.f, 0.f, 0.f, 0.f};
        ((float4*)out)[(gb - 640) * 256 + tid] = z;   // 32 blocks x 4KB = 128KB
    }
}

// ---------------- kernel F: LDS-staged K, den + scatter + fused pooling -----
// grid (32 q-stripes, 16 hb) = 512 blocks, 512 threads = 8 waves, 64 q/block.
// Load-balance swizzle: xm = hb>=8 ? 31-x : x pairs heavy/light triangles on
// each CU (linear blocks b and b+256 co-reside).
// Sloc is INT fixed-point: HIP atomicAdd on __shared__ float compiles to a
// CAS retry loop on gfx950 (r15: 5x k_F regression); int lowers to native
// fire-and-forget ds_add_u32. Keep the histogram in int.
// NOTE (r13 lesson): no manual reg-staging of K — compiler pipelines better.
// phase 1: den over all k, chunk-major (4 x 32KB LDS chunks); pair combine.
// phase 2: triangle scatter into 2048-bin int Sloc, chunks descending
//          (chunk 3 resident from phase 1), j-parity split within wave pair.
// phase 3: pooling is linear in S -> 3-tap stencil on this block's partials,
//          float atomics into out (reciprocal-multiply, RFPSCALE folded).
__global__ __launch_bounds__(512) void k_F(const __bf16* __restrict__ Qb,
                                           const __bf16* __restrict__ Kb,
                                           const float* __restrict__ w,
                                           float* __restrict__ out) {
    __shared__ __align__(16) __bf16 Kl[512 * HD];    // 32 KB
    __shared__ __align__(16) float  wl[2048];        // 8 KB
    __shared__ __align__(16) int    Sloc[2048];      // 8 KB
    __shared__ float dred[128];

    int hb = blockIdx.y;
    int xm = (hb >= 8) ? (31 - blockIdx.x) : blockIdx.x;   // load-balance swizzle
    int q0 = xm << 6;                            // 64 q rows per block
    int tid = threadIdx.x;
    int wid = tid >> 6, lane = tid & 63;
    int lm = lane & 15, lq = lane >> 4;
    int g = wid >> 1, h = wid & 1;               // 4 q-groups x 2 k-halves
    int qg0 = q0 + g * 16;

    int4 z4 = {0, 0, 0, 0};
    ((int4*)Sloc)[tid] = z4;                     // 512*16B = 8KB

    const __bf16* Qhb = Qb + hb * LSEQ * HD;
    const __bf16* Khb = Kb + hb * LSEQ * HD;

    // stage w[hb] (8KB, coalesced)
    ((float4*)wl)[tid] = ((const float4*)(w + hb * LSEQ))[tid];

    bf8_t aq = *(const bf8_t*)(Qhb + (qg0 + lm) * HD + lq * 8);

    // ---- phase 1: denominators over all k, chunk-staged ----
    float dsum[4] = {0.f, 0.f, 0.f, 0.f};
    for (int c = 0; c < 4; c++) {
        __syncthreads();                         // prior chunk compute done
        const int4* gsrc = (const int4*)(Khb + c * 512 * HD);
        #pragma unroll
        for (int i = 0; i < 4; i++) {
            int idx = tid + i * 512;
            ((int4*)Kl)[idx] = gsrc[idx];        // 32KB coalesced
        }
        __syncthreads();
        #pragma unroll 4
        for (int sl = h; sl < 32; sl += 2) {     // 16 subtiles per wave
            bf8_t bk_ = *(const bf8_t*)&Kl[(sl * 16 + lm) * HD + lq * 8];
            f4_t z = {0.f, 0.f, 0.f, 0.f};
            f4_t sc = __builtin_amdgcn_mfma_f32_16x16x32_bf16(aq, bk_, z, 0, 0, 0);
            #pragma unroll
            for (int r = 0; r < 4; r++) dsum[r] += fexp2(sc[r]);
        }
    }
    #pragma unroll
    for (int r = 0; r < 4; r++) {
        float v = dsum[r];
        v += __shfl_xor(v, 1);
        v += __shfl_xor(v, 2);
        v += __shfl_xor(v, 4);
        v += __shfl_xor(v, 8);
        dsum[r] = v;
    }
    if (lm == 0) {
        #pragma unroll
        for (int r = 0; r < 4; r++) dred[wid * 16 + lq * 4 + r] = dsum[r];
    }
    __syncthreads();
    float rdv[4];
    #pragma unroll
    for (int r = 0; r < 4; r++) {
        int base = g * 32 + lq * 4 + r;          // pair (g,h=0)+(g,h=1)
        rdv[r] = 1.0f / (dred[base] + dred[base + 16]);
    }

    // ---- phase 2: triangle scatter, chunks descending (3 is resident) ----
    int jb = qg0 >> 4;                           // boundary subtile index
    int c0 = q0 >> 9;                            // first chunk with k >= q0
    int qrow = qg0 + lq * 4;
    for (int c = 3; c >= c0; c--) {
        if (c != 3) {
            __syncthreads();
            const int4* gsrc = (const int4*)(Khb + c * 512 * HD);
            #pragma unroll
            for (int i = 0; i < 4; i++) {
                int idx = tid + i * 512;
                ((int4*)Kl)[idx] = gsrc[idx];
            }
            __syncthreads();
        }
        int jlo = jb > c * 32 ? jb : c * 32;
        int jhi = (c + 1) * 32;
        int js = jlo + ((jlo ^ h) & 1);          // first j with j&1 == h
        for (int j = js; j < jhi; j += 2) {
            int krow = j * 16 - c * 512 + lm;    // row within chunk
            bf8_t bk_ = *(const bf8_t*)&Kl[krow * HD + lq * 8];
            f4_t z = {0.f, 0.f, 0.f, 0.f};
            f4_t sc = __builtin_amdgcn_mfma_f32_16x16x32_bf16(aq, bk_, z, 0, 0, 0);
            float wv = wl[j * 16 + lm];
            int base = j * 16 + lm - qrow;       // m for r=0
            if (j == jb) {                       // boundary: mask m>=0
                #pragma unroll
                for (int r = 0; r < 4; r++) {
                    int m = base - r;
                    if (m >= 0) {
                        int iv = __float2int_rn(fexp2(sc[r]) * rdv[r] * wv);
                        atomicAdd(&Sloc[m], iv);
                    }
                }
            } else {                             // strictly above diagonal
                #pragma unroll
                for (int r = 0; r < 4; r++) {
                    int iv = __float2int_rn(fexp2(sc[r]) * rdv[r] * wv);
                    atomicAdd(&Sloc[base - r], iv);
                }
            }
        }
    }
    __syncthreads();

    // ---- phase 3: fused pooling — stencil on partials, float atomics ----
    // out[(b*2048+m)*8+h] += (Sloc[m-1]+Sloc[m]+Sloc[m+1]) * scale(edge)
    const float SC3 = RFPSCALE * (1.0f / 3.0f);
    const float SC2 = RFPSCALE * 0.5f;
    int hh = hb >> 1, b = hb & 1;
    float* obase = out + (b * LSEQ) * 8 + hh;
    int M = LSEQ - q0;                           // bins [0,M) are (possibly) set
    int top = (M + 1 < LSEQ) ? M + 1 : LSEQ;     // stencil reach
    for (int m = tid; m < top; m += 512) {
        int s = Sloc[m];
        float sc = SC3;
        if (m > 0) s += Sloc[m - 1]; else sc = SC2;
        if (m < LSEQ - 1) s += Sloc[m + 1]; else sc = SC2;
        if (s != 0)
            atomicAdd(&obase[m * 8], (float)s * sc);
    }
}

extern "C" void kernel_launch(void* const* d_in, const int* in_sizes, int n_in,
                              void* d_out, int out_size, void* d_ws, size_t ws_size,
                              hipStream_t stream) {
    const float* x  = (const float*)d_in[0];
    const float* pe = (const float*)d_in[1];
    const float* Wq = (const float*)d_in[2];
    const float* bq = (const float*)d_in[3];
    const float* Wk = (const float*)d_in[4];
    const float* bk = (const float*)d_in[5];
    const float* Wv = (const float*)d_in[6];
    float* out = (float*)d_out;

    char* ws = (char*)d_ws;
    float*  w   = (float*)(ws);                            // 128 KB
    __bf16* Qb  = (__bf16*)(ws + 131072);                  // 2 MB
    __bf16* Kb  = (__bf16*)(ws + 131072 + 2097152);        // 2 MB

    k_A<<<672, 256, 0, stream>>>(x, pe, Wq, Wk, Wv, bq, bk, w, Qb, Kb, out);
    k_F<<<dim3(32, 16), 512, 0, stream>>>(Qb, Kb, w, out);
}